// Round 6
// baseline (111.984 us; speedup 1.0000x reference)
//
#include <hip/hip_runtime.h>

// ContrastiveLoss cosine: B=4096 rows, D=1024, fp32.
// out layout: [0]=loss, [1..B]=i2t_cosine, [1+B..2B]=t2i_cosine (identical values).
// ws: unused (loss accumulated directly into out[0] via atomicAdd).
//
// Round-6 structure: single kernel. 2 rows per 256-thread block (128 thr/row,
// 12 independent dwordx4 loads/thread), per-row triplet -> one pre-scaled
// atomicAdd(out[0]) per block. No device fences (R3's -30us lesson: fenced
// last-block tails flush L2 per block; bare device-scope atomicAdd doesn't).
// out[0] zeroed by a 4-byte hipMemsetAsync (graph-capture-safe) replacing the
// whole k_reduce dispatch + its gap. Atomic-order noise on the loss is ~3e-6
// RMS (2048 partials of ~6e-4), an order below the accepted 1.5e-5 absmax.

constexpr int B = 4096;
constexpr int D = 1024;
constexpr int NBLK = B / 2;   // 2048 blocks
#define EPSF 1e-8f
#define MARGIN 0.2f

__device__ __forceinline__ float waveReduceSum(float v) {
#pragma unroll
    for (int off = 32; off > 0; off >>= 1)
        v += __shfl_xor(v, off, 64);
    return v;
}

__device__ __forceinline__ float dot4(float4 a, float4 b) {
    return a.x * b.x + a.y * b.y + a.z * b.z + a.w * b.w;
}

__global__ __launch_bounds__(256) void fused_all(
    const float* __restrict__ img, const float* __restrict__ txt,
    const int* __restrict__ ci, const int* __restrict__ ct,
    float* __restrict__ out) {
    const int t = threadIdx.x;
    const int sub = t >> 7;        // row within block (0,1)
    const int u = t & 127;         // float4 slot 0..127 (owns u and u+128)
    const int wave = t >> 6;       // 0..3
    const int lane = t & 63;
    const int row = blockIdx.x * 2 + sub;

    const int c0 = ci[row * 2 + 0];
    const int c1 = ci[row * 2 + 1];
    const int e0 = ct[row * 2 + 0];
    const int e1 = ct[row * 2 + 1];

    const float4* __restrict__ ib = (const float4*)(img + (size_t)row * D);
    const float4* __restrict__ tb = (const float4*)(txt + (size_t)row * D);
    const float4* __restrict__ i0 = (const float4*)(img + (size_t)c0 * D);
    const float4* __restrict__ i1 = (const float4*)(img + (size_t)c1 * D);
    const float4* __restrict__ t0 = (const float4*)(txt + (size_t)e0 * D);
    const float4* __restrict__ t1 = (const float4*)(txt + (size_t)e1 * D);

    // 12 independent 16B loads
    const float4 Aa = ib[u], Ab = ib[u + 128];
    const float4 Ta = tb[u], Tb = tb[u + 128];
    const float4 X0a = i0[u], X0b = i0[u + 128];
    const float4 X1a = i1[u], X1b = i1[u + 128];
    const float4 Y0a = t0[u], Y0b = t0[u + 128];
    const float4 Y1a = t1[u], Y1b = t1[u + 128];

    // 11 partial dot-products:
    //   [0] img.txt  [1] |img|^2  [2] |txt|^2
    //   [3] txt.img[c0] [4] txt.img[c1] [5] |img[c0]|^2 [6] |img[c1]|^2
    //   [7] img.txt[e0] [8] img.txt[e1] [9] |txt[e0]|^2 [10] |txt[e1]|^2
    float v[11];
    v[0]  = dot4(Aa, Ta)  + dot4(Ab, Tb);
    v[1]  = dot4(Aa, Aa)  + dot4(Ab, Ab);
    v[2]  = dot4(Ta, Ta)  + dot4(Tb, Tb);
    v[3]  = dot4(Ta, X0a) + dot4(Tb, X0b);
    v[4]  = dot4(Ta, X1a) + dot4(Tb, X1b);
    v[5]  = dot4(X0a, X0a) + dot4(X0b, X0b);
    v[6]  = dot4(X1a, X1a) + dot4(X1b, X1b);
    v[7]  = dot4(Aa, Y0a) + dot4(Ab, Y0b);
    v[8]  = dot4(Aa, Y1a) + dot4(Ab, Y1b);
    v[9]  = dot4(Y0a, Y0a) + dot4(Y0b, Y0b);
    v[10] = dot4(Y1a, Y1a) + dot4(Y1b, Y1b);

#pragma unroll
    for (int i = 0; i < 11; ++i) v[i] = waveReduceSum(v[i]);

    __shared__ float s[4][11];     // per-wave partials
    __shared__ float strip[2];     // per-row triplet values
    if (lane == 0) {
#pragma unroll
        for (int i = 0; i < 11; ++i) s[wave][i] = v[i];
    }
    __syncthreads();

    if (u == 0) {                  // one leader thread per row (t==0, t==128)
        const int w0 = sub * 2;
        float f[11];
#pragma unroll
        for (int i = 0; i < 11; ++i) f[i] = s[w0][i] + s[w0 + 1][i];

        const float na = sqrtf(f[1]);   // ||img[row]||
        const float nb = sqrtf(f[2]);   // ||txt[row]||
        const float prod = na * nb;
        const float cosv = f[0] / prod;                    // unclamped (sim)
        const float pos = 1.f - f[0] / fmaxf(prod, EPSF);  // clamped (dist)
        // t2i negative: anchor txt[row] vs img candidates ('<=': later wins ties)
        const float d0 = 1.f - f[3] / fmaxf(nb * sqrtf(f[5]), EPSF);
        const float d1 = 1.f - f[4] / fmaxf(nb * sqrtf(f[6]), EPSF);
        const float t2i_neg = (d1 <= d0) ? d1 : d0;
        // i2t negative: anchor img[row] vs txt candidates
        const float g0 = 1.f - f[7] / fmaxf(na * sqrtf(f[9]), EPSF);
        const float g1 = 1.f - f[8] / fmaxf(na * sqrtf(f[10]), EPSF);
        const float i2t_neg = (g1 <= g0) ? g1 : g0;

        out[1 + row] = cosv;          // i2t_cosine
        out[1 + B + row] = cosv;      // t2i_cosine (identical by construction)
        strip[sub] = fmaxf(pos - i2t_neg + MARGIN, 0.f)
                   + fmaxf(pos - t2i_neg + MARGIN, 0.f);
    }
    __syncthreads();
    if (t == 0)
        atomicAdd(out, (strip[0] + strip[1]) * (1.0f / (float)B));
}

extern "C" void kernel_launch(void* const* d_in, const int* in_sizes, int n_in,
                              void* d_out, int out_size, void* d_ws, size_t ws_size,
                              hipStream_t stream) {
    const float* img = (const float*)d_in[0];
    const float* txt = (const float*)d_in[1];
    // d_in[2]=labels (unused), d_in[3]=locations (unused)
    const int* ci = (const int*)d_in[4];
    const int* ct = (const int*)d_in[5];
    float* out = (float*)d_out;

    hipMemsetAsync(out, 0, sizeof(float), stream);  // zero out[0] (loss accumulator)
    fused_all<<<NBLK, 256, 0, stream>>>(img, txt, ci, ct, out);
}

// Round 8
// 93.933 us; speedup vs baseline: 1.1922x; 1.1922x over previous
//
#include <hip/hip_runtime.h>

// ContrastiveLoss cosine: B=4096 rows, D=1024, fp32.
// out layout: [0]=loss, [1..B]=i2t_cosine, [1+B..2B]=t2i_cosine (identical values).
// ws layout (floats): trip[B].
//
// FINAL (round-8 == round-7 resubmit; R7 bench was a broker timeout, no data).
// Verbatim round-2 structure — best measured (93.4 us). Search record:
// 1024blk/4wave+loop = 93.4 | 4096blk flat = 96.1 | 2048blk 12-load = 96.2 |
// fenced last-block tail = 123.7 (-30us: device-fence = L2 writeback/block) |
// single-address atomic tail = 112.0 (-16us: 2048 same-address RMWs serialize,
// drain after uniform-work blocks all finish). Two-kernel split with a
// deterministic 1-block reduce is the cheapest tail. Remaining total is
// ~72us harness poison/restore floor + ~7us kernel HBM floor (44.5MB fetch)
// + ~8us gather-latency residual + dispatch gaps.

constexpr int B = 4096;
constexpr int D = 1024;
#define EPSF 1e-8f
#define MARGIN 0.2f

__device__ __forceinline__ float waveReduceSum(float v) {
#pragma unroll
    for (int off = 32; off > 0; off >>= 1)
        v += __shfl_xor(v, off, 64);
    return v;
}

__device__ __forceinline__ float dot4(float4 a, float4 b) {
    return a.x * b.x + a.y * b.y + a.z * b.z + a.w * b.w;
}

// One wave (64 lanes) per row; 4 waves per 256-thread block.
// Per row, 11 dot-products over D=1024 in a single read pass of 6 rows:
//   sd = img.txt          s1 = |img|^2        s2 = |txt|^2
//   a0/a1 = txt.img[c]    q0/q1 = |img[c]|^2   (t2i negatives)
//   a2/a3 = img.txt[e]    r0/r1 = |txt[e]|^2   (i2t negatives)
__global__ __launch_bounds__(256) void fused_rows(
    const float* __restrict__ img, const float* __restrict__ txt,
    const int* __restrict__ ci, const int* __restrict__ ct,
    float* __restrict__ out, float* __restrict__ trip) {
    const int wave = threadIdx.x >> 6;
    const int lane = threadIdx.x & 63;
    const int row = blockIdx.x * 4 + wave;

    const int c0 = ci[row * 2 + 0];
    const int c1 = ci[row * 2 + 1];
    const int e0 = ct[row * 2 + 0];
    const int e1 = ct[row * 2 + 1];

    const float4* __restrict__ ib = (const float4*)(img + (size_t)row * D);
    const float4* __restrict__ tb = (const float4*)(txt + (size_t)row * D);
    const float4* __restrict__ i0 = (const float4*)(img + (size_t)c0 * D);
    const float4* __restrict__ i1 = (const float4*)(img + (size_t)c1 * D);
    const float4* __restrict__ t0 = (const float4*)(txt + (size_t)e0 * D);
    const float4* __restrict__ t1 = (const float4*)(txt + (size_t)e1 * D);

    float sd = 0.f, s1 = 0.f, s2 = 0.f;
    float a0 = 0.f, a1 = 0.f, a2 = 0.f, a3 = 0.f;
    float q0 = 0.f, q1 = 0.f, r0 = 0.f, r1 = 0.f;
#pragma unroll
    for (int j = 0; j < 4; ++j) {
        const int idx = j * 64 + lane;  // 256 float4 per row
        float4 A = ib[idx];
        float4 T = tb[idx];
        float4 X0 = i0[idx];
        float4 X1 = i1[idx];
        float4 Y0 = t0[idx];
        float4 Y1 = t1[idx];
        sd += dot4(A, T);
        s1 += dot4(A, A);
        s2 += dot4(T, T);
        a0 += dot4(T, X0);
        q0 += dot4(X0, X0);
        a1 += dot4(T, X1);
        q1 += dot4(X1, X1);
        a2 += dot4(A, Y0);
        r0 += dot4(Y0, Y0);
        a3 += dot4(A, Y1);
        r1 += dot4(Y1, Y1);
    }
    sd = waveReduceSum(sd);
    s1 = waveReduceSum(s1);
    s2 = waveReduceSum(s2);
    a0 = waveReduceSum(a0);
    a1 = waveReduceSum(a1);
    a2 = waveReduceSum(a2);
    a3 = waveReduceSum(a3);
    q0 = waveReduceSum(q0);
    q1 = waveReduceSum(q1);
    r0 = waveReduceSum(r0);
    r1 = waveReduceSum(r1);

    if (lane == 0) {
        const float na = sqrtf(s1);   // ||img[row]||
        const float nb = sqrtf(s2);   // ||txt[row]||
        const float prod = na * nb;
        const float cosv = sd / prod;                  // unclamped (sim)
        const float pos = 1.f - sd / fmaxf(prod, EPSF);  // clamped (dist)
        // t2i negative: anchor txt[row] vs img candidates ('<=': later wins ties)
        const float d0 = 1.f - a0 / fmaxf(nb * sqrtf(q0), EPSF);
        const float d1 = 1.f - a1 / fmaxf(nb * sqrtf(q1), EPSF);
        const float t2i_neg = (d1 <= d0) ? d1 : d0;
        // i2t negative: anchor img[row] vs txt candidates
        const float g0 = 1.f - a2 / fmaxf(na * sqrtf(r0), EPSF);
        const float g1 = 1.f - a3 / fmaxf(na * sqrtf(r1), EPSF);
        const float i2t_neg = (g1 <= g0) ? g1 : g0;

        out[1 + row] = cosv;          // i2t_cosine
        out[1 + B + row] = cosv;      // t2i_cosine (identical by construction)
        trip[row] = fmaxf(pos - i2t_neg + MARGIN, 0.f)
                  + fmaxf(pos - t2i_neg + MARGIN, 0.f);
    }
}

// Deterministic reduction of trip[B] -> loss = sum / B.
__global__ __launch_bounds__(1024) void k_reduce(
    const float* __restrict__ trip, float* __restrict__ out) {
    __shared__ float s[1024];
    const int t = threadIdx.x;
    float v = trip[t] + trip[t + 1024] + trip[t + 2048] + trip[t + 3072];
    s[t] = v;
    __syncthreads();
#pragma unroll
    for (int off = 512; off >= 64; off >>= 1) {
        if (t < off) s[t] += s[t + off];
        __syncthreads();
    }
    if (t < 64) {
        float x = s[t];
        x = waveReduceSum(x);
        if (t == 0) out[0] = x * (1.0f / (float)B);
    }
}

extern "C" void kernel_launch(void* const* d_in, const int* in_sizes, int n_in,
                              void* d_out, int out_size, void* d_ws, size_t ws_size,
                              hipStream_t stream) {
    const float* img = (const float*)d_in[0];
    const float* txt = (const float*)d_in[1];
    // d_in[2]=labels (unused), d_in[3]=locations (unused)
    const int* ci = (const int*)d_in[4];
    const int* ct = (const int*)d_in[5];
    float* out = (float*)d_out;
    float* trip = (float*)d_ws;

    fused_rows<<<B / 4, 256, 0, stream>>>(img, txt, ci, ct, out, trip);
    k_reduce<<<1, 1024, 0, stream>>>(trip, out);
}